// Round 6
// baseline (5824.043 us; speedup 1.0000x reference)
//
#include <hip/hip_runtime.h>
#include <math.h>

#define LTOK 10000
#define NBR 3
#define DM 512
#define DI 1024
#define DS 64
#define NH 16
#define HD 64
#define DXBC 1152      // DI + 2*DS
#define DPROJ 2192     // 2*DI + 2*DS + NH
#define NCH_MAX 200

typedef __attribute__((ext_vector_type(8))) short bf16x8;
typedef __attribute__((ext_vector_type(4))) float f32x4;

__device__ __forceinline__ float silu_f(float v){ return v / (1.f + expf(-v)); }

__device__ __forceinline__ unsigned short bf16_rn(float x){
    unsigned int u = __float_as_uint(x);
    u += 0x7FFF + ((u >> 16) & 1);
    return (unsigned short)(u >> 16);
}
__device__ __forceinline__ float bf16_tof(unsigned short h){
    return __uint_as_float(((unsigned int)h) << 16);
}

// ---------------- fp32 GEMM (fallback + attn) ----------------
template<int ACT, bool ADDRES, bool BIAS>
__global__ __launch_bounds__(256)
void gemm_k(const float* __restrict__ A, const float* __restrict__ W,
            const float* __restrict__ bias, float* __restrict__ C,
            int M, int N, int K, int lda, int ldc)
{
    const int m0 = blockIdx.y * 64, n0 = blockIdx.x * 64;
    __shared__ float As[16][64];
    __shared__ float Bs[16][64];
    const int tid = threadIdx.x;
    const int lr = tid >> 2, lk = (tid & 3) << 2;
    const int tx = tid & 15, ty = tid >> 4;
    float acc[4][4] = {};
    const int am = m0 + lr, bn = n0 + lr;
    const float* Ap = A + (long)am * lda + lk;
    const float* Wp = W + (long)bn * K + lk;
    for (int k0 = 0; k0 < K; k0 += 16) {
        float4 av = make_float4(0.f,0.f,0.f,0.f);
        float4 bv = make_float4(0.f,0.f,0.f,0.f);
        if (am < M) av = *(const float4*)(Ap + k0);
        if (bn < N) bv = *(const float4*)(Wp + k0);
        __syncthreads();
        As[lk+0][lr]=av.x; As[lk+1][lr]=av.y; As[lk+2][lr]=av.z; As[lk+3][lr]=av.w;
        Bs[lk+0][lr]=bv.x; Bs[lk+1][lr]=bv.y; Bs[lk+2][lr]=bv.z; Bs[lk+3][lr]=bv.w;
        __syncthreads();
        #pragma unroll
        for (int kk = 0; kk < 16; ++kk) {
            const float4 a = *(const float4*)&As[kk][ty << 2];
            const float4 b = *(const float4*)&Bs[kk][tx << 2];
            const float ar[4] = {a.x, a.y, a.z, a.w};
            const float brr[4] = {b.x, b.y, b.z, b.w};
            #pragma unroll
            for (int i = 0; i < 4; ++i)
                #pragma unroll
                for (int j = 0; j < 4; ++j)
                    acc[i][j] = fmaf(ar[i], brr[j], acc[i][j]);
        }
    }
    #pragma unroll
    for (int i = 0; i < 4; ++i) {
        const int m = m0 + (ty << 2) + i;
        const int n = n0 + (tx << 2);
        if (m < M && n + 4 <= N) {
            float4 v = make_float4(acc[i][0], acc[i][1], acc[i][2], acc[i][3]);
            if (BIAS) {
                const float4 bb = *(const float4*)(bias + n);
                v.x += bb.x; v.y += bb.y; v.z += bb.z; v.w += bb.w;
            }
            if (ACT == 1) { v.x=fmaxf(v.x,0.f); v.y=fmaxf(v.y,0.f); v.z=fmaxf(v.z,0.f); v.w=fmaxf(v.w,0.f); }
            if (ACT == 2) { v.x=tanhf(v.x); v.y=tanhf(v.y); v.z=tanhf(v.z); v.w=tanhf(v.w); }
            float* cp = C + (long)m * ldc + n;
            if (ADDRES) {
                const float4 o = *(const float4*)cp;
                v.x += o.x; v.y += o.y; v.z += o.z; v.w += o.w;
            }
            *(float4*)cp = v;
        }
    }
}

// ---------------- fp32 -> bf16 (hi|lo) split conversion ----------------
__global__ void cvt_split_k(const float* __restrict__ A, int lda, int M, int K,
                            unsigned short* __restrict__ A2, int lda2)
{
    const int kq = K >> 2;
    const long idx = (long)blockIdx.x * 256 + threadIdx.x;
    if (idx >= (long)M * kq) return;
    const int m = (int)(idx / kq);
    const int k4 = (int)(idx % kq) << 2;
    const float4 v = *(const float4*)(A + (long)m * lda + k4);
    ushort4 hi, lo;
    hi.x = bf16_rn(v.x); lo.x = bf16_rn(v.x - bf16_tof(hi.x));
    hi.y = bf16_rn(v.y); lo.y = bf16_rn(v.y - bf16_tof(hi.y));
    hi.z = bf16_rn(v.z); lo.z = bf16_rn(v.z - bf16_tof(hi.z));
    hi.w = bf16_rn(v.w); lo.w = bf16_rn(v.w - bf16_tof(hi.w));
    *(ushort4*)(A2 + (long)m * lda2 + k4) = hi;
    *(ushort4*)(A2 + (long)m * lda2 + K + k4) = lo;
}

// ---------------- bf16-split MFMA GEMM ----------------
template<int ACT, bool ADDRES, bool BIAS>
__global__ __launch_bounds__(256)
void gemm_mfma_k(const unsigned short* __restrict__ A2, int lda2,
                 const unsigned short* __restrict__ W2, int ldw2,
                 const float* __restrict__ bias, float* __restrict__ C,
                 int M, int N, int K, int ldc)
{
    __shared__ __align__(16) unsigned short As[128 * 72];
    __shared__ __align__(16) unsigned short Bs[128 * 72];
    const int tid = threadIdx.x;
    const int m0 = blockIdx.y << 7, n0 = blockIdx.x << 7;
    const int l = tid & 63, w = tid >> 6;
    const int wm = (w >> 1) << 6, wn = (w & 1) << 6;
    const int lr = l & 15, lk = (l >> 4) << 3;
    f32x4 acc[4][4];
    const f32x4 zf = {0.f, 0.f, 0.f, 0.f};
    #pragma unroll
    for (int i = 0; i < 4; ++i)
        #pragma unroll
        for (int j = 0; j < 4; ++j) acc[i][j] = zf;

    const int KS = K >> 6;
    const int S = 3 * KS;
    uint4 ra[4], rb[4];
    const uint4 zu = {0u, 0u, 0u, 0u};

    int crow[4], cseg[4];
    #pragma unroll
    for (int i = 0; i < 4; ++i) {
        const int c = tid + (i << 8);
        crow[i] = c >> 3; cseg[i] = c & 7;
    }

    auto preload = [&](int s, uint4 pa[4], uint4 pb[4]) {
        const int seg = s / KS;
        const int k0 = (s % KS) << 6;
        const int ao = k0 + (seg == 2 ? K : 0);
        const int wo = k0 + (seg == 1 ? K : 0);
        #pragma unroll
        for (int i = 0; i < 4; ++i) {
            const int gm = m0 + crow[i];
            const int gn = n0 + crow[i];
            const int ke = cseg[i] << 3;
            pa[i] = zu; pb[i] = zu;
            if (gm < M) pa[i] = *(const uint4*)(A2 + (long)gm * lda2 + ao + ke);
            if (gn < N) pb[i] = *(const uint4*)(W2 + (long)gn * ldw2 + wo + ke);
        }
    };

    preload(0, ra, rb);
    for (int s = 0; s < S; ++s) {
        __syncthreads();
        #pragma unroll
        for (int i = 0; i < 4; ++i) {
            const int off = crow[i] * 72 + (cseg[i] << 3);
            *(uint4*)(As + off) = ra[i];
            *(uint4*)(Bs + off) = rb[i];
        }
        __syncthreads();
        uint4 na[4], nb[4];
        if (s + 1 < S) preload(s + 1, na, nb);
        #pragma unroll
        for (int kh = 0; kh < 2; ++kh) {
            bf16x8 af[4], bfr[4];
            #pragma unroll
            for (int f = 0; f < 4; ++f)
                af[f] = *(const bf16x8*)(As + (wm + (f << 4) + lr) * 72 + (kh << 5) + lk);
            #pragma unroll
            for (int f = 0; f < 4; ++f)
                bfr[f] = *(const bf16x8*)(Bs + (wn + (f << 4) + lr) * 72 + (kh << 5) + lk);
            #pragma unroll
            for (int fm = 0; fm < 4; ++fm)
                #pragma unroll
                for (int fn = 0; fn < 4; ++fn)
                    acc[fm][fn] = __builtin_amdgcn_mfma_f32_16x16x32_bf16(
                        af[fm], bfr[fn], acc[fm][fn], 0, 0, 0);
        }
        #pragma unroll
        for (int i = 0; i < 4; ++i) { ra[i] = na[i]; rb[i] = nb[i]; }
    }

    #pragma unroll
    for (int fm = 0; fm < 4; ++fm) {
        #pragma unroll
        for (int fn = 0; fn < 4; ++fn) {
            const int n = n0 + wn + (fn << 4) + lr;
            float bv = 0.f;
            if (BIAS && n < N) bv = bias[n];
            #pragma unroll
            for (int j = 0; j < 4; ++j) {
                const int m = m0 + wm + (fm << 4) + ((l >> 4) << 2) + j;
                if (m < M && n < N) {
                    float v = acc[fm][fn][j];
                    if (BIAS) v += bv;
                    float* cp = C + (long)m * ldc + n;
                    if (ADDRES) v += *cp;
                    if (ACT == 1) v = fmaxf(v, 0.f);
                    if (ACT == 2) v = tanhf(v);
                    *cp = v;
                }
            }
        }
    }
}

// ---------------- branch construction ----------------
__global__ void build_branches_k(const float* __restrict__ h0, float* __restrict__ hb)
{
    const long idx = (long)blockIdx.x * 256 + threadIdx.x;
    if (idx >= (long)LTOK * DM) return;
    const int t = (int)(idx >> 9);
    const int d = (int)(idx & 511);
    const float v = h0[idx];
    hb[idx] = v;
    hb[(long)LTOK * DM + (long)t * DM + (511 - d)] = v;
    const int q = t / 100, r = t % 100;
    hb[(long)2 * LTOK * DM + (long)(r * 100 + q) * DM + d] = v;
}

// ---------------- conv1d+silu for 128 B/C channels -> compact [t][128] --------
__global__ void convBC_k(const float* __restrict__ zx, const float* __restrict__ cw,
                         const float* __restrict__ cb, float* __restrict__ xc, int lay)
{
    const int idx = blockIdx.x * 256 + threadIdx.x;   // LTOK*32
    const int c4 = idx & 31;
    const int t  = idx >> 5;
    const int cx = 1024 + c4 * 4;
    const float* wp = cw + ((long)lay * DXBC + cx) * 4;
    const float4 w0 = *(const float4*)(wp);
    const float4 w1 = *(const float4*)(wp + 4);
    const float4 w2 = *(const float4*)(wp + 8);
    const float4 w3 = *(const float4*)(wp + 12);
    float4 acc = *(const float4*)(cb + (long)lay * DXBC + cx);
    const float* base = zx + (long)t * DPROJ + 1024 + cx;
    if (t >= 3) { const float4 xv = *(const float4*)(base - 3 * DPROJ);
        acc.x=fmaf(xv.x,w0.x,acc.x); acc.y=fmaf(xv.y,w1.x,acc.y); acc.z=fmaf(xv.z,w2.x,acc.z); acc.w=fmaf(xv.w,w3.x,acc.w); }
    if (t >= 2) { const float4 xv = *(const float4*)(base - 2 * DPROJ);
        acc.x=fmaf(xv.x,w0.y,acc.x); acc.y=fmaf(xv.y,w1.y,acc.y); acc.z=fmaf(xv.z,w2.y,acc.z); acc.w=fmaf(xv.w,w3.y,acc.w); }
    if (t >= 1) { const float4 xv = *(const float4*)(base - 1 * DPROJ);
        acc.x=fmaf(xv.x,w0.z,acc.x); acc.y=fmaf(xv.y,w1.z,acc.y); acc.z=fmaf(xv.z,w2.z,acc.z); acc.w=fmaf(xv.w,w3.z,acc.w); }
    { const float4 xv = *(const float4*)(base);
        acc.x=fmaf(xv.x,w0.w,acc.x); acc.y=fmaf(xv.y,w1.w,acc.y); acc.z=fmaf(xv.z,w2.w,acc.z); acc.w=fmaf(xv.w,w3.w,acc.w); }
    acc.x = silu_f(acc.x); acc.y = silu_f(acc.y); acc.z = silu_f(acc.z); acc.w = silu_f(acc.w);
    *(float4*)(xc + (long)t * 128 + c4 * 4) = acc;
}

// ---------------- dt softplus + dA ----------------
__global__ void dt_k(const float* __restrict__ zx, const float* __restrict__ dt_bias,
                     const float* __restrict__ A_log, float* __restrict__ dtv,
                     float* __restrict__ dAv, int lay)
{
    const int idx = blockIdx.x * 256 + threadIdx.x;   // LTOK*16
    const int hh = idx & 15;
    const int t  = idx >> 4;
    const float v = zx[(long)t * DPROJ + 2176 + hh] + dt_bias[lay * NH + hh];
    const float dt = v > 20.f ? v : log1pf(expf(v));
    dtv[idx] = dt;
    dAv[idx] = expf(-dt * expf(A_log[lay * NH + hh]));
}

// ---------------- halo save (must run BEFORE scan_local writes y) ----------------
__global__ void halo_k(const float* __restrict__ zx, float* __restrict__ xh,
                       int LC, int NCH)
{
    const int idx = blockIdx.x * 256 + threadIdx.x;   // NCH*1024
    if (idx >= NCH * 1024) return;
    const int hp = idx & 1023;
    const int ch = idx >> 10;
    const int t0 = ch * LC;
    float a = 0.f, b = 0.f, c = 0.f;
    if (t0 < LTOK) {
        if (t0 >= 3) a = zx[(long)(t0-3) * DPROJ + 1024 + hp];
        if (t0 >= 2) b = zx[(long)(t0-2) * DPROJ + 1024 + hp];
        if (t0 >= 1) c = zx[(long)(t0-1) * DPROJ + 1024 + hp];
    }
    const int h = hp >> 6, p = hp & 63;
    float* o = xh + ((long)(h * NCH + ch) * HD + p) * 3;
    o[0] = a; o[1] = b; o[2] = c;
}

// ================= chunked SSD scan =================
struct Slot { float4 b0,b1,b2,b3,c0,c1,c2,c3; float x, dt, da; };

__device__ __forceinline__ void slot_load(Slot& S, const float* __restrict__ zx,
                                          const float* __restrict__ xc,
                                          const float* __restrict__ dtp,
                                          const float* __restrict__ dAp,
                                          int t, int hp, int n0)
{
    S.x = zx[(long)t * DPROJ + 1024 + hp];
    const float* Bp = xc + (long)t * 128 + n0;
    S.b0 = *(const float4*)(Bp);     S.b1 = *(const float4*)(Bp + 4);
    S.b2 = *(const float4*)(Bp + 8); S.b3 = *(const float4*)(Bp + 12);
    const float* Cp = Bp + 64;
    S.c0 = *(const float4*)(Cp);     S.c1 = *(const float4*)(Cp + 4);
    S.c2 = *(const float4*)(Cp + 8); S.c3 = *(const float4*)(Cp + 12);
    S.dt = dtp[(long)t * NH]; S.da = dAp[(long)t * NH];
}

// state update + tree-reduced y partial (depth-4 instead of 16-deep chain)
__device__ __forceinline__ float slot_step_tree(const Slot& S, float s[16], float dtx)
{
    const float da = S.da;
    s[0] =fmaf(da,s[0] ,dtx*S.b0.x); s[1] =fmaf(da,s[1] ,dtx*S.b0.y);
    s[2] =fmaf(da,s[2] ,dtx*S.b0.z); s[3] =fmaf(da,s[3] ,dtx*S.b0.w);
    s[4] =fmaf(da,s[4] ,dtx*S.b1.x); s[5] =fmaf(da,s[5] ,dtx*S.b1.y);
    s[6] =fmaf(da,s[6] ,dtx*S.b1.z); s[7] =fmaf(da,s[7] ,dtx*S.b1.w);
    s[8] =fmaf(da,s[8] ,dtx*S.b2.x); s[9] =fmaf(da,s[9] ,dtx*S.b2.y);
    s[10]=fmaf(da,s[10],dtx*S.b2.z); s[11]=fmaf(da,s[11],dtx*S.b2.w);
    s[12]=fmaf(da,s[12],dtx*S.b3.x); s[13]=fmaf(da,s[13],dtx*S.b3.y);
    s[14]=fmaf(da,s[14],dtx*S.b3.z); s[15]=fmaf(da,s[15],dtx*S.b3.w);
    float u0 = s[0]*S.c0.x,  u1 = s[1]*S.c0.y,  u2 = s[2]*S.c0.z,  u3 = s[3]*S.c0.w;
    float u4 = s[4]*S.c1.x,  u5 = s[5]*S.c1.y,  u6 = s[6]*S.c1.z,  u7 = s[7]*S.c1.w;
    float u8 = s[8]*S.c2.x,  u9 = s[9]*S.c2.y,  u10= s[10]*S.c2.z, u11= s[11]*S.c2.w;
    float u12= s[12]*S.c3.x, u13= s[13]*S.c3.y, u14= s[14]*S.c3.z, u15= s[15]*S.c3.w;
    u0 += u1;  u2 += u3;  u4 += u5;  u6 += u7;
    u8 += u9;  u10+= u11; u12+= u13; u14+= u15;
    u0 += u2;  u4 += u6;  u8 += u10; u12+= u14;
    u0 += u4;  u8 += u12;
    return u0 + u8;
}

// fused local scan: writes y_local into zx, stores end-state/decay/cumAt
__global__ __launch_bounds__(256)
void scan_local_k(float* __restrict__ zx, const float* __restrict__ xc,
                  const float* __restrict__ dtv, const float* __restrict__ dAv,
                  const float* __restrict__ cw, const float* __restrict__ cb,
                  const float* __restrict__ Dh,
                  float* __restrict__ Sl, float* __restrict__ Pc,
                  const float* __restrict__ xh, float* __restrict__ cumAt,
                  int lay, int LC, int NCH)
{
    const int h = blockIdx.x, ch = blockIdx.y;
    const int tid = threadIdx.x;
    const int p = tid >> 2, g = tid & 3, n0 = g << 4;
    const int hp = h * HD + p;
    const int t0 = ch * LC;
    const int t1 = min(t0 + LC, LTOK);
    float s[16];
    #pragma unroll
    for (int i = 0; i < 16; ++i) s[i] = 0.f;
    float cumA = 1.f;
    if (t0 < t1) {
        const float dcoef = Dh[lay * NH + h];
        const float4 wt = *(const float4*)(cw + ((long)lay * DXBC + hp) * 4);
        const float cbv = cb[(long)lay * DXBC + hp];
        const float* xhp = xh + ((long)(h * NCH + ch) * HD + p) * 3;
        float xw0 = xhp[0], xw1 = xhp[1], xw2 = xhp[2];
        float* yp = zx + 1024 + h * HD;
        float* cap = cumAt + (long)h * LTOK;
        const float* dtp = dtv + h;
        const float* dAp = dAv + h;
        Slot SA, SB;
        slot_load(SA, zx, xc, dtp, dAp, t0, hp, n0);
        slot_load(SB, zx, xc, dtp, dAp, min(t0 + 1, LTOK - 1), hp, n0);
        for (int t = t0; t < t1; t += 2) {
            Slot NA;
            slot_load(NA, zx, xc, dtp, dAp, min(t + 2, LTOK - 1), hp, n0);
            {
                float xcv = fmaf(wt.x, xw0, cbv); xcv = fmaf(wt.y, xw1, xcv);
                xcv = fmaf(wt.z, xw2, xcv);       xcv = fmaf(wt.w, SA.x, xcv);
                const float xs = silu_f(xcv);
                float ys = slot_step_tree(SA, s, SA.dt * xs);
                ys += __shfl_xor(ys, 1); ys += __shfl_xor(ys, 2);
                cumA *= SA.da;
                if (g == 0) yp[(long)t * DPROJ + p] = ys + dcoef * xs;
                if (tid == 0) cap[t] = cumA;
                xw0 = xw1; xw1 = xw2; xw2 = SA.x;
            }
            SA = NA;
            Slot NB;
            slot_load(NB, zx, xc, dtp, dAp, min(t + 3, LTOK - 1), hp, n0);
            if (t + 1 < t1) {
                float xcv = fmaf(wt.x, xw0, cbv); xcv = fmaf(wt.y, xw1, xcv);
                xcv = fmaf(wt.z, xw2, xcv);       xcv = fmaf(wt.w, SB.x, xcv);
                const float xs = silu_f(xcv);
                float ys = slot_step_tree(SB, s, SB.dt * xs);
                ys += __shfl_xor(ys, 1); ys += __shfl_xor(ys, 2);
                cumA *= SB.da;
                if (g == 0) yp[(long)(t + 1) * DPROJ + p] = ys + dcoef * xs;
                if (tid == 0) cap[t + 1] = cumA;
                xw0 = xw1; xw1 = xw2; xw2 = SB.x;
            }
            SB = NB;
        }
    }
    float* sp = Sl + (long)(h * NCH + ch) * 4096 + p * 64 + n0;
    *(float4*)(sp)    = make_float4(s[0], s[1], s[2], s[3]);
    *(float4*)(sp+4)  = make_float4(s[4], s[5], s[6], s[7]);
    *(float4*)(sp+8)  = make_float4(s[8], s[9], s[10],s[11]);
    *(float4*)(sp+12) = make_float4(s[12],s[13],s[14],s[15]);
    if (tid == 0) Pc[h * NCH + ch] = cumA;
}

// sequential chunk combine (prefetched); Sl[ch] := incoming state of chunk ch
__global__ __launch_bounds__(256)
void combine_k(float* __restrict__ Sl, const float* __restrict__ Pc, int NCH)
{
    const int h = blockIdx.x;
    const int tid = threadIdx.x;
    float run[16];
    #pragma unroll
    for (int i = 0; i < 16; ++i) run[i] = 0.f;
    float* base = Sl + (long)h * NCH * 4096 + tid * 16;
    float4 c0 = *(const float4*)(base),   c1 = *(const float4*)(base+4);
    float4 c2 = *(const float4*)(base+8), c3 = *(const float4*)(base+12);
    float pc = Pc[h * NCH];
    for (int ch = 0; ch < NCH; ++ch) {
        float4 n0v=c0, n1v=c1, n2v=c2, n3v=c3; float pcn = pc;
        if (ch + 1 < NCH) {
            const float* nb = base + (long)(ch + 1) * 4096;
            n0v = *(const float4*)(nb);   n1v = *(const float4*)(nb+4);
            n2v = *(const float4*)(nb+8); n3v = *(const float4*)(nb+12);
            pcn = Pc[h * NCH + ch + 1];
        }
        float* bp = base + (long)ch * 4096;
        *(float4*)(bp)    = make_float4(run[0], run[1], run[2], run[3]);
        *(float4*)(bp+4)  = make_float4(run[4], run[5], run[6], run[7]);
        *(float4*)(bp+8)  = make_float4(run[8], run[9], run[10],run[11]);
        *(float4*)(bp+12) = make_float4(run[12],run[13],run[14],run[15]);
        run[0] =fmaf(pc,run[0] ,c0.x); run[1] =fmaf(pc,run[1] ,c0.y);
        run[2] =fmaf(pc,run[2] ,c0.z); run[3] =fmaf(pc,run[3] ,c0.w);
        run[4] =fmaf(pc,run[4] ,c1.x); run[5] =fmaf(pc,run[5] ,c1.y);
        run[6] =fmaf(pc,run[6] ,c1.z); run[7] =fmaf(pc,run[7] ,c1.w);
        run[8] =fmaf(pc,run[8] ,c2.x); run[9] =fmaf(pc,run[9] ,c2.y);
        run[10]=fmaf(pc,run[10],c2.z); run[11]=fmaf(pc,run[11],c2.w);
        run[12]=fmaf(pc,run[12],c3.x); run[13]=fmaf(pc,run[13],c3.y);
        run[14]=fmaf(pc,run[14],c3.z); run[15]=fmaf(pc,run[15],c3.w);
        c0=n0v; c1=n1v; c2=n2v; c3=n3v; pc = pcn;
    }
}

// fully parallel correction: y[t] += cumAt[t] * (C_t . S_in)
__global__ __launch_bounds__(256)
void correct_k(float* __restrict__ zx, const float* __restrict__ xc,
               const float* __restrict__ Sl, const float* __restrict__ cumAt,
               int LC, int NCH)
{
    const int h = blockIdx.x, ch = blockIdx.y;
    const int t0 = ch * LC;
    if (t0 >= LTOK || ch == 0) return;      // chunk 0 has zero incoming state
    const int t1 = min(t0 + LC, LTOK);
    const int tid = threadIdx.x;
    const int p = tid >> 2, g = tid & 3, n0 = g << 4;
    const float* sp = Sl + (long)(h * NCH + ch) * 4096 + p * 64 + n0;
    const float4 s0 = *(const float4*)(sp),   s1 = *(const float4*)(sp+4);
    const float4 s2 = *(const float4*)(sp+8), s3 = *(const float4*)(sp+12);
    float* yp = zx + 1024 + h * HD;
    const float* ca = cumAt + (long)h * LTOK;
    for (int t = t0; t < t1; ++t) {
        const float* Cp = xc + (long)t * 128 + 64 + n0;
        const float4 c0 = *(const float4*)(Cp),   c1 = *(const float4*)(Cp+4);
        const float4 c2 = *(const float4*)(Cp+8), c3 = *(const float4*)(Cp+12);
        float u0 = s0.x*c0.x, u1 = s0.y*c0.y, u2 = s0.z*c0.z, u3 = s0.w*c0.w;
        float u4 = s1.x*c1.x, u5 = s1.y*c1.y, u6 = s1.z*c1.z, u7 = s1.w*c1.w;
        float u8 = s2.x*c2.x, u9 = s2.y*c2.y, u10= s2.z*c2.z, u11= s2.w*c2.w;
        float u12= s3.x*c3.x, u13= s3.y*c3.y, u14= s3.z*c3.z, u15= s3.w*c3.w;
        u0+=u1; u2+=u3; u4+=u5; u6+=u7; u8+=u9; u10+=u11; u12+=u13; u14+=u15;
        u0+=u2; u4+=u6; u8+=u10; u12+=u14;
        u0+=u4; u8+=u12;
        float d = u0 + u8;
        d += __shfl_xor(d, 1); d += __shfl_xor(d, 2);
        if (g == 0) yp[(long)t * DPROJ + p] += ca[t] * d;
    }
}

// ---------------- serial fallback scan ----------------
__global__ __launch_bounds__(256)
void scan_serial_k(float* __restrict__ zx, const float* __restrict__ xc,
                   const float* __restrict__ dtv, const float* __restrict__ dAv,
                   const float* __restrict__ cw, const float* __restrict__ cb,
                   const float* __restrict__ Dh, int lay)
{
    const int h = blockIdx.x;
    const float dcoef = Dh[lay * NH + h];
    const int tid = threadIdx.x;
    const int p = tid >> 2, g = tid & 3, n0 = g << 4;
    const int hp = h * HD + p;
    const float4 wt = *(const float4*)(cw + ((long)lay * DXBC + hp) * 4);
    const float cbv = cb[(long)lay * DXBC + hp];
    float xw0 = 0.f, xw1 = 0.f, xw2 = 0.f;
    float s[16];
    #pragma unroll
    for (int i = 0; i < 16; ++i) s[i] = 0.f;
    float* yp = zx + 1024 + h * HD;
    const float* dtp = dtv + h;
    const float* dAp = dAv + h;
    Slot SA, SB;
    slot_load(SA, zx, xc, dtp, dAp, 0, hp, n0);
    slot_load(SB, zx, xc, dtp, dAp, 1, hp, n0);
    for (int t = 0; t < LTOK; t += 2) {
        Slot NA;
        slot_load(NA, zx, xc, dtp, dAp, min(t + 2, LTOK - 1), hp, n0);
        {
            float xcv = fmaf(wt.x, xw0, cbv); xcv = fmaf(wt.y, xw1, xcv);
            xcv = fmaf(wt.z, xw2, xcv);       xcv = fmaf(wt.w, SA.x, xcv);
            const float xs = silu_f(xcv);
            float ys = slot_step_tree(SA, s, SA.dt * xs);
            ys += __shfl_xor(ys, 1); ys += __shfl_xor(ys, 2);
            if (g == 0) yp[(long)t * DPROJ + p] = ys + dcoef * xs;
            xw0 = xw1; xw1 = xw2; xw2 = SA.x;
        }
        SA = NA;
        Slot NB;
        slot_load(NB, zx, xc, dtp, dAp, min(t + 3, LTOK - 1), hp, n0);
        if (t + 1 < LTOK) {
            float xcv = fmaf(wt.x, xw0, cbv); xcv = fmaf(wt.y, xw1, xcv);
            xcv = fmaf(wt.z, xw2, xcv);       xcv = fmaf(wt.w, SB.x, xcv);
            const float xs = silu_f(xcv);
            float ys = slot_step_tree(SB, s, SB.dt * xs);
            ys += __shfl_xor(ys, 1); ys += __shfl_xor(ys, 2);
            if (g == 0) yp[(long)(t + 1) * DPROJ + p] = ys + dcoef * xs;
            xw0 = xw1; xw1 = xw2; xw2 = SB.x;
        }
        SB = NB;
    }
}

// ---------------- gate + RMSNorm (in zx) ----------------
__global__ __launch_bounds__(256)
void gate_rms_k(float* __restrict__ zx, const float* __restrict__ nw, int lay)
{
    const int row = blockIdx.x;
    const int tid = threadIdx.x;
    float* base = zx + (long)row * DPROJ;
    const float4 yv = *(const float4*)(base + 1024 + tid * 4);
    const float4 zv = *(const float4*)(base + tid * 4);
    float4 gg;
    gg.x = yv.x * silu_f(zv.x); gg.y = yv.y * silu_f(zv.y);
    gg.z = yv.z * silu_f(zv.z); gg.w = yv.w * silu_f(zv.w);
    float ss = gg.x*gg.x + gg.y*gg.y + gg.z*gg.z + gg.w*gg.w;
    #pragma unroll
    for (int o = 1; o < 64; o <<= 1) ss += __shfl_xor(ss, o);
    __shared__ float red[4];
    if ((tid & 63) == 0) red[tid >> 6] = ss;
    __syncthreads();
    const float tot = red[0] + red[1] + red[2] + red[3];
    const float r = rsqrtf(tot * (1.f / 1024.f) + 1e-5f);
    const float4 w = *(const float4*)(nw + (long)lay * DI + tid * 4);
    gg.x *= r * w.x; gg.y *= r * w.y; gg.z *= r * w.z; gg.w *= r * w.w;
    *(float4*)(base + 1024 + tid * 4) = gg;
}

// ---------------- LayerNorm (512) ----------------
__global__ void ln_k(const float* __restrict__ h, const float* __restrict__ w,
                     const float* __restrict__ b, float* __restrict__ o)
{
    const int t = blockIdx.x;
    const int tid = threadIdx.x;   // 128
    const float* row = h + (long)t * DM;
    const float4 v = *(const float4*)(row + tid * 4);
    float s1 = v.x + v.y + v.z + v.w;
    float s2 = v.x*v.x + v.y*v.y + v.z*v.z + v.w*v.w;
    #pragma unroll
    for (int oo = 1; oo < 64; oo <<= 1) { s1 += __shfl_xor(s1, oo); s2 += __shfl_xor(s2, oo); }
    __shared__ float r1[2], r2[2];
    if ((tid & 63) == 0) { r1[tid >> 6] = s1; r2[tid >> 6] = s2; }
    __syncthreads();
    s1 = r1[0] + r1[1]; s2 = r2[0] + r2[1];
    const float mu = s1 * (1.f / 512.f);
    const float var = s2 * (1.f / 512.f) - mu * mu;
    const float rs = rsqrtf(var + 1e-5f);
    const float4 w4 = *(const float4*)(w + tid * 4);
    const float4 b4 = *(const float4*)(b + tid * 4);
    float4 out;
    out.x = (v.x - mu) * rs * w4.x + b4.x;
    out.y = (v.y - mu) * rs * w4.y + b4.y;
    out.z = (v.z - mu) * rs * w4.z + b4.z;
    out.w = (v.w - mu) * rs * w4.w + b4.w;
    *(float4*)(o + (long)t * DM + tid * 4) = out;
}

__global__ void score_k(const float* __restrict__ t1, const float* __restrict__ w2,
                        const float* __restrict__ b2, float* __restrict__ sc)
{
    const int tok = blockIdx.x * 4 + (threadIdx.x >> 6);
    const int lane = threadIdx.x & 63;
    const float2 v = *(const float2*)(t1 + (long)tok * 128 + lane * 2);
    const float2 w = *(const float2*)(w2 + lane * 2);
    float s = v.x * w.x + v.y * w.y;
    #pragma unroll
    for (int o = 1; o < 64; o <<= 1) s += __shfl_xor(s, o);
    if (lane == 0) sc[tok] = s + b2[0];
}

__global__ void softmax_k(float* __restrict__ sc, int n)
{
    const int tid = threadIdx.x;   // 1024
    float m = -1e30f;
    for (int i = tid; i < n; i += 1024) m = fmaxf(m, sc[i]);
    #pragma unroll
    for (int o = 1; o < 64; o <<= 1) m = fmaxf(m, __shfl_xor(m, o));
    __shared__ float red[16];
    if ((tid & 63) == 0) red[tid >> 6] = m;
    __syncthreads();
    float M = red[0];
    #pragma unroll
    for (int i = 1; i < 16; ++i) M = fmaxf(M, red[i]);
    float s = 0.f;
    for (int i = tid; i < n; i += 1024) s += expf(sc[i] - M);
    #pragma unroll
    for (int o = 1; o < 64; o <<= 1) s += __shfl_xor(s, o);
    __shared__ float red2[16];
    if ((tid & 63) == 0) red2[tid >> 6] = s;
    __syncthreads();
    float S = 0.f;
    #pragma unroll
    for (int i = 0; i < 16; ++i) S += red2[i];
    const float inv = 1.f / S;
    for (int i = tid; i < n; i += 1024) sc[i] = expf(sc[i] - M) * inv;
}

__global__ void zero_k(float* __restrict__ p) { p[threadIdx.x] = 0.f; }

__global__ void pool_k(const float* __restrict__ hn, const float* __restrict__ sc,
                       float* __restrict__ pooled)
{
    const int d = threadIdx.x;       // 512
    const int t0 = blockIdx.x * 500; // 60 blocks
    float acc = 0.f;
    for (int t = t0; t < t0 + 500; ++t)
        acc = fmaf(sc[t], hn[(long)t * DM + d], acc);
    atomicAdd(&pooled[d], acc);
}

__global__ void head_k(const float* __restrict__ pooled, const float* __restrict__ cw,
                       const float* __restrict__ cb, float* __restrict__ out)
{
    const int lane = threadIdx.x;    // 64
    float a0 = 0.f, a1 = 0.f;
    for (int d = lane; d < 512; d += 64) {
        const float pv = pooled[d];
        a0 = fmaf(pv, cw[d], a0);
        a1 = fmaf(pv, cw[512 + d], a1);
    }
    #pragma unroll
    for (int o = 1; o < 64; o <<= 1) { a0 += __shfl_xor(a0, o); a1 += __shfl_xor(a1, o); }
    if (lane == 0) {
        const float l0 = a0 + cb[0], l1 = a1 + cb[1];
        out[0] = l0; out[1] = l1;
        const float m = fmaxf(l0, l1);
        const float e0 = expf(l0 - m), e1 = expf(l1 - m);
        const float inv = 1.f / (e0 + e1);
        out[2] = e0 * inv; out[3] = e1 * inv;
    }
}

extern "C" void kernel_launch(void* const* d_in, const int* in_sizes, int n_in,
                              void* d_out, int out_size, void* d_ws, size_t ws_size,
                              hipStream_t stream)
{
    const float* x         = (const float*)d_in[0];
    const float* fc1_w     = (const float*)d_in[1];
    const float* fc1_b     = (const float*)d_in[2];
    const float* in_proj_w = (const float*)d_in[3];
    const float* conv_w    = (const float*)d_in[4];
    const float* conv_b    = (const float*)d_in[5];
    const float* dt_bias   = (const float*)d_in[6];
    const float* A_log     = (const float*)d_in[7];
    const float* Dh        = (const float*)d_in[8];
    const float* norm_w    = (const float*)d_in[9];
    const float* out_proj_w= (const float*)d_in[10];
    const float* ln_w      = (const float*)d_in[11];
    const float* ln_b      = (const float*)d_in[12];
    const float* attn_w1   = (const float*)d_in[13];
    const float* attn_b1   = (const float*)d_in[14];
    const float* attn_w2   = (const float*)d_in[15];
    const float* attn_b2   = (const float*)d_in[16];
    const float* cls_w     = (const float*)d_in[17];
    const float* cls_b     = (const float*)d_in[18];
    float* out = (float*)d_out;

    // ---- workspace layout (floats) ----
    float* ws = (float*)d_ws;
    float* hb    = ws;                                 // 15,360,000
    float* zx    = hb    + 15360000L;                  // 21,920,000
    float* xc    = zx    + 21920000L;                  // 1,280,000
    float* dtv   = xc    + 1280000L;                   // 160,000
    float* dAv   = dtv   + 160000L;                    // 160,000
    float* cumAt = dAv   + 160000L;                    // 160,000
    float* w2f   = cumAt + 160000L;                    // 1,122,304
    float* big   = w2f   + 1122304L;                   // A2 | (Sl,Pc,xh)
    const long fixed_f = 15360000L + 21920000L + 1280000L + 160000L + 160000L
                       + 160000L + 1122304L;
    const long bigf = (long)(ws_size / 4) - fixed_f;

    int NCH = 0;
    if (bigf > 3200) NCH = (int)((bigf - 3200) / 68608L);
    if (NCH > NCH_MAX) NCH = NCH_MAX;
    const int LC = (NCH >= 2) ? (LTOK + NCH - 1) / NCH : LTOK;
    float* Sl = big;
    float* Pc = big + (long)NCH * 65536L;
    float* xh = Pc + (long)NH * NCH;

    const bool USE_MFMA = (bigf >= 5130000L);
    unsigned short* A2u = (unsigned short*)big;
    unsigned short* W2u = (unsigned short*)w2f;

    float* h0  = zx;
    float* hn  = zx;
    float* t1  = zx + (long)NBR * LTOK * DM;
    float* sc  = t1 + (long)NBR * LTOK * 128;
    float* pooled = sc + NBR * LTOK;

    // ---- 1. FC1 + ReLU ----
    if (USE_MFMA) {
        for (int kp = 0; kp < 2; ++kp) {
            cvt_split_k<<<dim3((LTOK * 128 + 255) / 256), 256, 0, stream>>>(
                x + kp * 512, 1024, LTOK, 512, A2u, 1024);
            cvt_split_k<<<dim3((512 * 128 + 255) / 256), 256, 0, stream>>>(
                fc1_w + kp * 512, 1024, 512, 512, W2u, 1024);
            if (kp == 0)
                gemm_mfma_k<0, false, true><<<dim3(4, 79), 256, 0, stream>>>(
                    A2u, 1024, W2u, 1024, fc1_b, h0, LTOK, DM, 512, DM);
            else
                gemm_mfma_k<1, true, false><<<dim3(4, 79), 256, 0, stream>>>(
                    A2u, 1024, W2u, 1024, nullptr, h0, LTOK, DM, 512, DM);
        }
    } else {
        gemm_k<1, false, true><<<dim3(8, 157), 256, 0, stream>>>(
            x, fc1_w, fc1_b, h0, LTOK, DM, 1024, 1024, DM);
    }

    // ---- 2. build 3 branch streams ----
    build_branches_k<<<dim3((LTOK * DM + 255) / 256), 256, 0, stream>>>(h0, hb);

    // ---- 3. mamba phase: 3 branches x 2 layers ----
    for (int br = 0; br < NBR; ++br) {
        for (int ml = 0; ml < 2; ++ml) {
            const int lay = br * 2 + ml;
            if (USE_MFMA) {
                cvt_split_k<<<dim3((LTOK * 128 + 255) / 256), 256, 0, stream>>>(
                    hb + (long)br * LTOK * DM, 512, LTOK, 512, A2u, 1024);
                cvt_split_k<<<dim3((DPROJ * 128 + 255) / 256), 256, 0, stream>>>(
                    in_proj_w + (long)lay * DPROJ * DM, 512, DPROJ, 512, W2u, 1024);
                gemm_mfma_k<0, false, false><<<dim3(18, 79), 256, 0, stream>>>(
                    A2u, 1024, W2u, 1024, nullptr, zx, LTOK, DPROJ, 512, DPROJ);
            } else {
                gemm_k<0, false, false><<<dim3(35, 157), 256, 0, stream>>>(
                    hb + (long)br * LTOK * DM,
                    in_proj_w + (long)lay * DPROJ * DM, nullptr, zx,
                    LTOK, DPROJ, DM, DM, DPROJ);
            }
            convBC_k<<<dim3(LTOK * 32 / 256), 256, 0, stream>>>(zx, conv_w, conv_b, xc, lay);
            dt_k<<<dim3(LTOK * NH / 256), 256, 0, stream>>>(zx, dt_bias, A_log, dtv, dAv, lay);
            if (NCH >= 2) {
                halo_k<<<dim3((NCH * 1024 + 255) / 256), 256, 0, stream>>>(zx, xh, LC, NCH);
                scan_local_k<<<dim3(NH, NCH), 256, 0, stream>>>(
                    zx, xc, dtv, dAv, conv_w, conv_b, Dh, Sl, Pc, xh, cumAt, lay, LC, NCH);
                combine_k<<<dim3(NH), 256, 0, stream>>>(Sl, Pc, NCH);
                correct_k<<<dim3(NH, NCH), 256, 0, stream>>>(zx, xc, Sl, cumAt, LC, NCH);
            } else {
                scan_serial_k<<<dim3(NH), 256, 0, stream>>>(
                    zx, xc, dtv, dAv, conv_w, conv_b, Dh, lay);
            }
            gate_rms_k<<<dim3(LTOK), 256, 0, stream>>>(zx, norm_w, lay);
            if (USE_MFMA) {
                for (int kp = 0; kp < 2; ++kp) {
                    cvt_split_k<<<dim3((LTOK * 128 + 255) / 256), 256, 0, stream>>>(
                        zx + 1024 + kp * 512, DPROJ, LTOK, 512, A2u, 1024);
                    cvt_split_k<<<dim3((512 * 128 + 255) / 256), 256, 0, stream>>>(
                        out_proj_w + (long)lay * DM * DI + kp * 512, 1024, 512, 512, W2u, 1024);
                    gemm_mfma_k<0, true, false><<<dim3(4, 79), 256, 0, stream>>>(
                        A2u, 1024, W2u, 1024, nullptr, hb + (long)br * LTOK * DM,
                        LTOK, DM, 512, DM);
                }
            } else {
                gemm_k<0, true, false><<<dim3(8, 157), 256, 0, stream>>>(
                    zx + 1024, out_proj_w + (long)lay * DM * DI, nullptr,
                    hb + (long)br * LTOK * DM, LTOK, DM, DI, DPROJ, DM);
            }
        }
    }

    // ---- 4. final LN ----
    ln_k<<<dim3(NBR * LTOK), 128, 0, stream>>>(hb, ln_w, ln_b, hn);

    // ---- 5. attention scores (small; fp32) ----
    gemm_k<2, false, true><<<dim3(2, 469), 256, 0, stream>>>(
        hn, attn_w1, attn_b1, t1, NBR * LTOK, 128, DM, DM, 128);
    score_k<<<dim3(NBR * LTOK / 4), 256, 0, stream>>>(t1, attn_w2, attn_b2, sc);
    softmax_k<<<dim3(1), 1024, 0, stream>>>(sc, NBR * LTOK);

    // ---- 6. pooling + head ----
    zero_k<<<dim3(1), 512, 0, stream>>>(pooled);
    pool_k<<<dim3(60), 512, 0, stream>>>(hn, sc, pooled);
    head_k<<<dim3(1), 64, 0, stream>>>(pooled, cls_w, cls_b, out);
}

// Round 7
// 4266.398 us; speedup vs baseline: 1.3651x; 1.3651x over previous
//
#include <hip/hip_runtime.h>
#include <math.h>

#define LTOK 10000
#define NBR 3
#define DM 512
#define DI 1024
#define DS 64
#define NH 16
#define HD 64
#define DXBC 1152      // DI + 2*DS
#define DPROJ 2192     // 2*DI + 2*DS + NH
#define NCH_MAX 200

typedef __attribute__((ext_vector_type(8))) short bf16x8;
typedef __attribute__((ext_vector_type(4))) float f32x4;

__device__ __forceinline__ float silu_f(float v){ return v / (1.f + expf(-v)); }

__device__ __forceinline__ unsigned short bf16_rn(float x){
    unsigned int u = __float_as_uint(x);
    u += 0x7FFF + ((u >> 16) & 1);
    return (unsigned short)(u >> 16);
}
__device__ __forceinline__ float bf16_tof(unsigned short h){
    return __uint_as_float(((unsigned int)h) << 16);
}

// async global->LDS, 16B per lane; dest wave-uniform base + lane*16 (CK-style casts)
__device__ __forceinline__ void gload_lds16(const void* g, void* l)
{
    __builtin_amdgcn_global_load_lds(
        (const __attribute__((address_space(1))) void*)(unsigned long long)g,
        (__attribute__((address_space(3))) void*)(unsigned int)(unsigned long long)l,
        16, 0, 0);
}

// ---------------- fp32 GEMM (fallback + attn) ----------------
template<int ACT, bool ADDRES, bool BIAS>
__global__ __launch_bounds__(256)
void gemm_k(const float* __restrict__ A, const float* __restrict__ W,
            const float* __restrict__ bias, float* __restrict__ C,
            int M, int N, int K, int lda, int ldc)
{
    const int m0 = blockIdx.y * 64, n0 = blockIdx.x * 64;
    __shared__ float As[16][64];
    __shared__ float Bs[16][64];
    const int tid = threadIdx.x;
    const int lr = tid >> 2, lk = (tid & 3) << 2;
    const int tx = tid & 15, ty = tid >> 4;
    float acc[4][4] = {};
    const int am = m0 + lr, bn = n0 + lr;
    const float* Ap = A + (long)am * lda + lk;
    const float* Wp = W + (long)bn * K + lk;
    for (int k0 = 0; k0 < K; k0 += 16) {
        float4 av = make_float4(0.f,0.f,0.f,0.f);
        float4 bv = make_float4(0.f,0.f,0.f,0.f);
        if (am < M) av = *(const float4*)(Ap + k0);
        if (bn < N) bv = *(const float4*)(Wp + k0);
        __syncthreads();
        As[lk+0][lr]=av.x; As[lk+1][lr]=av.y; As[lk+2][lr]=av.z; As[lk+3][lr]=av.w;
        Bs[lk+0][lr]=bv.x; Bs[lk+1][lr]=bv.y; Bs[lk+2][lr]=bv.z; Bs[lk+3][lr]=bv.w;
        __syncthreads();
        #pragma unroll
        for (int kk = 0; kk < 16; ++kk) {
            const float4 a = *(const float4*)&As[kk][ty << 2];
            const float4 b = *(const float4*)&Bs[kk][tx << 2];
            const float ar[4] = {a.x, a.y, a.z, a.w};
            const float brr[4] = {b.x, b.y, b.z, b.w};
            #pragma unroll
            for (int i = 0; i < 4; ++i)
                #pragma unroll
                for (int j = 0; j < 4; ++j)
                    acc[i][j] = fmaf(ar[i], brr[j], acc[i][j]);
        }
    }
    #pragma unroll
    for (int i = 0; i < 4; ++i) {
        const int m = m0 + (ty << 2) + i;
        const int n = n0 + (tx << 2);
        if (m < M && n + 4 <= N) {
            float4 v = make_float4(acc[i][0], acc[i][1], acc[i][2], acc[i][3]);
            if (BIAS) {
                const float4 bb = *(const float4*)(bias + n);
                v.x += bb.x; v.y += bb.y; v.z += bb.z; v.w += bb.w;
            }
            if (ACT == 1) { v.x=fmaxf(v.x,0.f); v.y=fmaxf(v.y,0.f); v.z=fmaxf(v.z,0.f); v.w=fmaxf(v.w,0.f); }
            if (ACT == 2) { v.x=tanhf(v.x); v.y=tanhf(v.y); v.z=tanhf(v.z); v.w=tanhf(v.w); }
            float* cp = C + (long)m * ldc + n;
            if (ADDRES) {
                const float4 o = *(const float4*)cp;
                v.x += o.x; v.y += o.y; v.z += o.z; v.w += o.w;
            }
            *(float4*)cp = v;
        }
    }
}

// ---------------- fp32 -> bf16 (hi|lo) split conversion ----------------
__global__ void cvt_split_k(const float* __restrict__ A, int lda, int M, int K,
                            unsigned short* __restrict__ A2, int lda2)
{
    const int kq = K >> 2;
    const long idx = (long)blockIdx.x * 256 + threadIdx.x;
    if (idx >= (long)M * kq) return;
    const int m = (int)(idx / kq);
    const int k4 = (int)(idx % kq) << 2;
    const float4 v = *(const float4*)(A + (long)m * lda + k4);
    ushort4 hi, lo;
    hi.x = bf16_rn(v.x); lo.x = bf16_rn(v.x - bf16_tof(hi.x));
    hi.y = bf16_rn(v.y); lo.y = bf16_rn(v.y - bf16_tof(hi.y));
    hi.z = bf16_rn(v.z); lo.z = bf16_rn(v.z - bf16_tof(hi.z));
    hi.w = bf16_rn(v.w); lo.w = bf16_rn(v.w - bf16_tof(hi.w));
    *(ushort4*)(A2 + (long)m * lda2 + k4) = hi;
    *(ushort4*)(A2 + (long)m * lda2 + K + k4) = lo;
}

// ---------------- bf16-split MFMA GEMM (gload_lds + 2-phase dbuf) ----------------
// C[M][ldc] (+)= act( sum of 3 segs A2 x W2^T + bias ); A2 [M][2K], W2 [N][2K]
template<int ACT, bool ADDRES, bool BIAS>
__global__ __launch_bounds__(256)
void gemm_mfma_k(const unsigned short* __restrict__ A2, int lda2,
                 const unsigned short* __restrict__ W2, int ldw2,
                 const float* __restrict__ bias, float* __restrict__ C,
                 int M, int N, int K, int ldc)
{
    __shared__ __align__(16) unsigned short As[2][128 * 64];   // 16KB x2
    __shared__ __align__(16) unsigned short Bs[2][128 * 64];
    const int tid = threadIdx.x;
    const int m0 = blockIdx.y << 7, n0 = blockIdx.x << 7;
    const int l = tid & 63, w = tid >> 6;
    const int wm = (w >> 1) << 6, wn = (w & 1) << 6;
    const int lr = l & 15, lk = (l >> 4) << 3;
    const int srow = l >> 3, scol = (l & 7) << 3;   // staging: 8 rows x 64 ushort per gload
    f32x4 acc[4][4];
    const f32x4 zf = {0.f, 0.f, 0.f, 0.f};
    #pragma unroll
    for (int i = 0; i < 4; ++i)
        #pragma unroll
        for (int j = 0; j < 4; ++j) acc[i][j] = zf;

    const int KS = K >> 6;
    const int S = 3 * KS;

    auto stage = [&](int s, int c) {
        int seg = 0, sk = s;
        if (sk >= KS) { seg = 1; sk -= KS; }
        if (sk >= KS) { seg = 2; sk -= KS; }
        const int k0 = sk << 6;
        const int ao = k0 + (seg == 2 ? K : 0);   // A uses lo in seg2
        const int wo = k0 + (seg == 1 ? K : 0);   // W uses lo in seg1
        #pragma unroll
        for (int j = 0; j < 4; ++j) {
            const int rb = (w << 5) + (j << 3);
            const int r = rb + srow;
            const long gm = min(m0 + r, M - 1);
            const long gn = min(n0 + r, N - 1);
            gload_lds16(A2 + gm * lda2 + ao + scol, &As[c][rb << 6]);
            gload_lds16(W2 + gn * ldw2 + wo + scol, &Bs[c][rb << 6]);
        }
    };

    int cur = 0;
    stage(0, 0);
    asm volatile("s_waitcnt vmcnt(0)" ::: "memory");
    __syncthreads();
    for (int s = 0; s < S; ++s) {
        if (s + 1 < S) stage(s + 1, cur ^ 1);    // prefetch next K-step into other buffer
        #pragma unroll
        for (int kh = 0; kh < 2; ++kh) {
            bf16x8 af[4], bfr[4];
            #pragma unroll
            for (int f = 0; f < 4; ++f)
                af[f] = *(const bf16x8*)(&As[cur][(wm + (f << 4) + lr) * 64 + (kh << 5) + lk]);
            #pragma unroll
            for (int f = 0; f < 4; ++f)
                bfr[f] = *(const bf16x8*)(&Bs[cur][(wn + (f << 4) + lr) * 64 + (kh << 5) + lk]);
            #pragma unroll
            for (int fm = 0; fm < 4; ++fm)
                #pragma unroll
                for (int fn = 0; fn < 4; ++fn)
                    acc[fm][fn] = __builtin_amdgcn_mfma_f32_16x16x32_bf16(
                        af[fm], bfr[fn], acc[fm][fn], 0, 0, 0);
        }
        asm volatile("s_waitcnt vmcnt(0)" ::: "memory");
        __syncthreads();
        cur ^= 1;
    }

    // epilogue: bias -> residual-add -> act
    #pragma unroll
    for (int fm = 0; fm < 4; ++fm) {
        #pragma unroll
        for (int fn = 0; fn < 4; ++fn) {
            const int n = n0 + wn + (fn << 4) + lr;
            float bv = 0.f;
            if (BIAS && n < N) bv = bias[n];
            #pragma unroll
            for (int j = 0; j < 4; ++j) {
                const int m = m0 + wm + (fm << 4) + ((l >> 4) << 2) + j;
                if (m < M && n < N) {
                    float v = acc[fm][fn][j];
                    if (BIAS) v += bv;
                    float* cp = C + (long)m * ldc + n;
                    if (ADDRES) v += *cp;
                    if (ACT == 1) v = fmaxf(v, 0.f);
                    if (ACT == 2) v = tanhf(v);
                    *cp = v;
                }
            }
        }
    }
}

// ---------------- branch construction ----------------
__global__ void build_branches_k(const float* __restrict__ h0, float* __restrict__ hb)
{
    const long idx = (long)blockIdx.x * 256 + threadIdx.x;
    if (idx >= (long)LTOK * DM) return;
    const int t = (int)(idx >> 9);
    const int d = (int)(idx & 511);
    const float v = h0[idx];
    hb[idx] = v;
    hb[(long)LTOK * DM + (long)t * DM + (511 - d)] = v;
    const int q = t / 100, r = t % 100;
    hb[(long)2 * LTOK * DM + (long)(r * 100 + q) * DM + d] = v;
}

// ---------------- conv1d+silu for 128 B/C channels -> compact [t][128] --------
__global__ void convBC_k(const float* __restrict__ zx, const float* __restrict__ cw,
                         const float* __restrict__ cb, float* __restrict__ xc, int lay)
{
    const int idx = blockIdx.x * 256 + threadIdx.x;   // LTOK*32
    const int c4 = idx & 31;
    const int t  = idx >> 5;
    const int cx = 1024 + c4 * 4;
    const float* wp = cw + ((long)lay * DXBC + cx) * 4;
    const float4 w0 = *(const float4*)(wp);
    const float4 w1 = *(const float4*)(wp + 4);
    const float4 w2 = *(const float4*)(wp + 8);
    const float4 w3 = *(const float4*)(wp + 12);
    float4 acc = *(const float4*)(cb + (long)lay * DXBC + cx);
    const float* base = zx + (long)t * DPROJ + 1024 + cx;
    if (t >= 3) { const float4 xv = *(const float4*)(base - 3 * DPROJ);
        acc.x=fmaf(xv.x,w0.x,acc.x); acc.y=fmaf(xv.y,w1.x,acc.y); acc.z=fmaf(xv.z,w2.x,acc.z); acc.w=fmaf(xv.w,w3.x,acc.w); }
    if (t >= 2) { const float4 xv = *(const float4*)(base - 2 * DPROJ);
        acc.x=fmaf(xv.x,w0.y,acc.x); acc.y=fmaf(xv.y,w1.y,acc.y); acc.z=fmaf(xv.z,w2.y,acc.z); acc.w=fmaf(xv.w,w3.y,acc.w); }
    if (t >= 1) { const float4 xv = *(const float4*)(base - 1 * DPROJ);
        acc.x=fmaf(xv.x,w0.z,acc.x); acc.y=fmaf(xv.y,w1.z,acc.y); acc.z=fmaf(xv.z,w2.z,acc.z); acc.w=fmaf(xv.w,w3.z,acc.w); }
    { const float4 xv = *(const float4*)(base);
        acc.x=fmaf(xv.x,w0.w,acc.x); acc.y=fmaf(xv.y,w1.w,acc.y); acc.z=fmaf(xv.z,w2.w,acc.z); acc.w=fmaf(xv.w,w3.w,acc.w); }
    acc.x = silu_f(acc.x); acc.y = silu_f(acc.y); acc.z = silu_f(acc.z); acc.w = silu_f(acc.w);
    *(float4*)(xc + (long)t * 128 + c4 * 4) = acc;
}

// ---------------- dt softplus + dA ----------------
__global__ void dt_k(const float* __restrict__ zx, const float* __restrict__ dt_bias,
                     const float* __restrict__ A_log, float* __restrict__ dtv,
                     float* __restrict__ dAv, int lay)
{
    const int idx = blockIdx.x * 256 + threadIdx.x;   // LTOK*16
    const int hh = idx & 15;
    const int t  = idx >> 4;
    const float v = zx[(long)t * DPROJ + 2176 + hh] + dt_bias[lay * NH + hh];
    const float dt = v > 20.f ? v : log1pf(expf(v));
    dtv[idx] = dt;
    dAv[idx] = expf(-dt * expf(A_log[lay * NH + hh]));
}

// ---------------- halo save (must run BEFORE scan_local writes y) ----------------
__global__ void halo_k(const float* __restrict__ zx, float* __restrict__ xh,
                       int LC, int NCH)
{
    const int idx = blockIdx.x * 256 + threadIdx.x;   // NCH*1024
    if (idx >= NCH * 1024) return;
    const int hp = idx & 1023;
    const int ch = idx >> 10;
    const int t0 = ch * LC;
    float a = 0.f, b = 0.f, c = 0.f;
    if (t0 < LTOK) {
        if (t0 >= 3) a = zx[(long)(t0-3) * DPROJ + 1024 + hp];
        if (t0 >= 2) b = zx[(long)(t0-2) * DPROJ + 1024 + hp];
        if (t0 >= 1) c = zx[(long)(t0-1) * DPROJ + 1024 + hp];
    }
    const int h = hp >> 6, p = hp & 63;
    float* o = xh + ((long)(h * NCH + ch) * HD + p) * 3;
    o[0] = a; o[1] = b; o[2] = c;
}

// ================= chunked SSD scan =================
struct Slot { float4 b0,b1,b2,b3,c0,c1,c2,c3; float x, dt, da; };

__device__ __forceinline__ void slot_load(Slot& S, const float* __restrict__ zx,
                                          const float* __restrict__ xc,
                                          const float* __restrict__ dtp,
                                          const float* __restrict__ dAp,
                                          int t, int hp, int n0)
{
    S.x = zx[(long)t * DPROJ + 1024 + hp];
    const float* Bp = xc + (long)t * 128 + n0;
    S.b0 = *(const float4*)(Bp);     S.b1 = *(const float4*)(Bp + 4);
    S.b2 = *(const float4*)(Bp + 8); S.b3 = *(const float4*)(Bp + 12);
    const float* Cp = Bp + 64;
    S.c0 = *(const float4*)(Cp);     S.c1 = *(const float4*)(Cp + 4);
    S.c2 = *(const float4*)(Cp + 8); S.c3 = *(const float4*)(Cp + 12);
    S.dt = dtp[(long)t * NH]; S.da = dAp[(long)t * NH];
}

__device__ __forceinline__ float slot_step_tree(const Slot& S, float s[16], float dtx)
{
    const float da = S.da;
    s[0] =fmaf(da,s[0] ,dtx*S.b0.x); s[1] =fmaf(da,s[1] ,dtx*S.b0.y);
    s[2] =fmaf(da,s[2] ,dtx*S.b0.z); s[3] =fmaf(da,s[3] ,dtx*S.b0.w);
    s[4] =fmaf(da,s[4] ,dtx*S.b1.x); s[5] =fmaf(da,s[5] ,dtx*S.b1.y);
    s[6] =fmaf(da,s[6] ,dtx*S.b1.z); s[7] =fmaf(da,s[7] ,dtx*S.b1.w);
    s[8] =fmaf(da,s[8] ,dtx*S.b2.x); s[9] =fmaf(da,s[9] ,dtx*S.b2.y);
    s[10]=fmaf(da,s[10],dtx*S.b2.z); s[11]=fmaf(da,s[11],dtx*S.b2.w);
    s[12]=fmaf(da,s[12],dtx*S.b3.x); s[13]=fmaf(da,s[13],dtx*S.b3.y);
    s[14]=fmaf(da,s[14],dtx*S.b3.z); s[15]=fmaf(da,s[15],dtx*S.b3.w);
    float u0 = s[0]*S.c0.x,  u1 = s[1]*S.c0.y,  u2 = s[2]*S.c0.z,  u3 = s[3]*S.c0.w;
    float u4 = s[4]*S.c1.x,  u5 = s[5]*S.c1.y,  u6 = s[6]*S.c1.z,  u7 = s[7]*S.c1.w;
    float u8 = s[8]*S.c2.x,  u9 = s[9]*S.c2.y,  u10= s[10]*S.c2.z, u11= s[11]*S.c2.w;
    float u12= s[12]*S.c3.x, u13= s[13]*S.c3.y, u14= s[14]*S.c3.z, u15= s[15]*S.c3.w;
    u0 += u1;  u2 += u3;  u4 += u5;  u6 += u7;
    u8 += u9;  u10+= u11; u12+= u13; u14+= u15;
    u0 += u2;  u4 += u6;  u8 += u10; u12+= u14;
    u0 += u4;  u8 += u12;
    return u0 + u8;
}

// fused local scan with LDS-staged B/C/x/dt (25-token groups)
__global__ __launch_bounds__(256)
void scan_local_k(float* __restrict__ zx, const float* __restrict__ xc,
                  const float* __restrict__ dtv, const float* __restrict__ dAv,
                  const float* __restrict__ cw, const float* __restrict__ cb,
                  const float* __restrict__ Dh,
                  float* __restrict__ Sl, float* __restrict__ Pc,
                  const float* __restrict__ xh, float* __restrict__ cumAt,
                  int lay, int LC, int NCH)
{
    const int h = blockIdx.x, ch = blockIdx.y;
    const int tid = threadIdx.x;
    const int p = tid >> 2, g = tid & 3, n0 = g << 4;
    const int hp = h * HD + p;
    const int t0 = ch * LC;
    const int t1 = min(t0 + LC, LTOK);
    __shared__ float bcS[25][128];   // B|C per token
    __shared__ float xS[25][64];     // raw x slice for this head
    __shared__ float dS[25][2];      // dt, dA
    float s[16];
    #pragma unroll
    for (int i = 0; i < 16; ++i) s[i] = 0.f;
    float cumA = 1.f;

    const float dcoef = Dh[lay * NH + h];
    const float4 wt = *(const float4*)(cw + ((long)lay * DXBC + hp) * 4);
    const float cbv = cb[(long)lay * DXBC + hp];
    const float* xhp = xh + ((long)(h * NCH + ch) * HD + p) * 3;
    float xw0 = xhp[0], xw1 = xhp[1], xw2 = xhp[2];
    float* yp = zx + 1024 + h * HD;
    float* cap = cumAt + (long)h * LTOK;

    auto stageg = [&](int g0, int n) {
        for (int i = tid; i < 800; i += 256) {               // 25x32 float4
            const int r = i >> 5, c4 = (i & 31) << 2;
            if (r < n) *(float4*)&bcS[r][c4] = *(const float4*)(xc + (long)(g0 + r) * 128 + c4);
        }
        for (int i = tid; i < 400; i += 256) {               // 25x16 float4
            const int r = i >> 4, c4 = (i & 15) << 2;
            if (r < n) *(float4*)&xS[r][c4] = *(const float4*)(zx + (long)(g0 + r) * DPROJ + 1024 + h * HD + c4);
        }
        if (tid < n) {
            dS[tid][0] = dtv[(long)(g0 + tid) * NH + h];
            dS[tid][1] = dAv[(long)(g0 + tid) * NH + h];
        }
    };

    int gt = t0;
    if (gt < t1) {
        stageg(gt, min(25, t1 - gt));
        __syncthreads();
        while (true) {
            const int n = min(25, t1 - gt);
            for (int r = 0; r < n; ++r) {
                const float4 b0 = *(const float4*)&bcS[r][n0 + 0];
                const float4 b1 = *(const float4*)&bcS[r][n0 + 4];
                const float4 b2 = *(const float4*)&bcS[r][n0 + 8];
                const float4 b3 = *(const float4*)&bcS[r][n0 + 12];
                const float4 c0 = *(const float4*)&bcS[r][64 + n0 + 0];
                const float4 c1 = *(const float4*)&bcS[r][64 + n0 + 4];
                const float4 c2 = *(const float4*)&bcS[r][64 + n0 + 8];
                const float4 c3 = *(const float4*)&bcS[r][64 + n0 + 12];
                const float xr = xS[r][p];
                const float dtc = dS[r][0], dac = dS[r][1];
                float xcv = fmaf(wt.x, xw0, cbv); xcv = fmaf(wt.y, xw1, xcv);
                xcv = fmaf(wt.z, xw2, xcv);       xcv = fmaf(wt.w, xr, xcv);
                const float xs = silu_f(xcv);
                const float dtx = dtc * xs;
                s[0] =fmaf(dac,s[0] ,dtx*b0.x); s[1] =fmaf(dac,s[1] ,dtx*b0.y);
                s[2] =fmaf(dac,s[2] ,dtx*b0.z); s[3] =fmaf(dac,s[3] ,dtx*b0.w);
                s[4] =fmaf(dac,s[4] ,dtx*b1.x); s[5] =fmaf(dac,s[5] ,dtx*b1.y);
                s[6] =fmaf(dac,s[6] ,dtx*b1.z); s[7] =fmaf(dac,s[7] ,dtx*b1.w);
                s[8] =fmaf(dac,s[8] ,dtx*b2.x); s[9] =fmaf(dac,s[9] ,dtx*b2.y);
                s[10]=fmaf(dac,s[10],dtx*b2.z); s[11]=fmaf(dac,s[11],dtx*b2.w);
                s[12]=fmaf(dac,s[12],dtx*b3.x); s[13]=fmaf(dac,s[13],dtx*b3.y);
                s[14]=fmaf(dac,s[14],dtx*b3.z); s[15]=fmaf(dac,s[15],dtx*b3.w);
                float u0 = s[0]*c0.x,  u1 = s[1]*c0.y,  u2 = s[2]*c0.z,  u3 = s[3]*c0.w;
                float u4 = s[4]*c1.x,  u5 = s[5]*c1.y,  u6 = s[6]*c1.z,  u7 = s[7]*c1.w;
                float u8 = s[8]*c2.x,  u9 = s[9]*c2.y,  u10= s[10]*c2.z, u11= s[11]*c2.w;
                float u12= s[12]*c3.x, u13= s[13]*c3.y, u14= s[14]*c3.z, u15= s[15]*c3.w;
                u0+=u1; u2+=u3; u4+=u5; u6+=u7; u8+=u9; u10+=u11; u12+=u13; u14+=u15;
                u0+=u2; u4+=u6; u8+=u10; u12+=u14;
                u0+=u4; u8+=u12;
                float ys = u0 + u8;
                ys += __shfl_xor(ys, 1); ys += __shfl_xor(ys, 2);
                cumA *= dac;
                if (g == 0) yp[(long)(gt + r) * DPROJ + p] = ys + dcoef * xs;
                if (tid == 0) cap[gt + r] = cumA;
                xw0 = xw1; xw1 = xw2; xw2 = xr;
            }
            gt += n;
            if (gt >= t1) break;
            __syncthreads();                 // readers done with LDS
            stageg(gt, min(25, t1 - gt));
            __syncthreads();                 // next group staged
        }
    }
    float* sp = Sl + (long)(h * NCH + ch) * 4096 + p * 64 + n0;
    *(float4*)(sp)    = make_float4(s[0], s[1], s[2], s[3]);
    *(float4*)(sp+4)  = make_float4(s[4], s[5], s[6], s[7]);
    *(float4*)(sp+8)  = make_float4(s[8], s[9], s[10],s[11]);
    *(float4*)(sp+12) = make_float4(s[12],s[13],s[14],s[15]);
    if (tid == 0) Pc[h * NCH + ch] = cumA;
}

// sequential chunk combine (prefetched); Sl[ch] := incoming state of chunk ch
__global__ __launch_bounds__(256)
void combine_k(float* __restrict__ Sl, const float* __restrict__ Pc, int NCH)
{
    const int h = blockIdx.x;
    const int tid = threadIdx.x;
    float run[16];
    #pragma unroll
    for (int i = 0; i < 16; ++i) run[i] = 0.f;
    float* base = Sl + (long)h * NCH * 4096 + tid * 16;
    float4 c0 = *(const float4*)(base),   c1 = *(const float4*)(base+4);
    float4 c2 = *(const float4*)(base+8), c3 = *(const float4*)(base+12);
    float pc = Pc[h * NCH];
    for (int ch = 0; ch < NCH; ++ch) {
        float4 n0v=c0, n1v=c1, n2v=c2, n3v=c3; float pcn = pc;
        if (ch + 1 < NCH) {
            const float* nb = base + (long)(ch + 1) * 4096;
            n0v = *(const float4*)(nb);   n1v = *(const float4*)(nb+4);
            n2v = *(const float4*)(nb+8); n3v = *(const float4*)(nb+12);
            pcn = Pc[h * NCH + ch + 1];
        }
        float* bp = base + (long)ch * 4096;
        *(float4*)(bp)    = make_float4(run[0], run[1], run[2], run[3]);
        *(float4*)(bp+4)  = make_float4(run[4], run[5], run[6], run[7]);
        *(float4*)(bp+8)  = make_float4(run[8], run[9], run[10],run[11]);
        *(float4*)(bp+12) = make_float4(run[12],run[13],run[14],run[15]);
        run[0] =fmaf(pc,run[0] ,c0.x); run[1] =fmaf(pc,run[1] ,c0.y);
        run[2] =fmaf(pc,run[2] ,c0.z); run[3] =fmaf(pc,run[3] ,c0.w);
        run[4] =fmaf(pc,run[4] ,c1.x); run[5] =fmaf(pc,run[5] ,c1.y);
        run[6] =fmaf(pc,run[6] ,c1.z); run[7] =fmaf(pc,run[7] ,c1.w);
        run[8] =fmaf(pc,run[8] ,c2.x); run[9] =fmaf(pc,run[9] ,c2.y);
        run[10]=fmaf(pc,run[10],c2.z); run[11]=fmaf(pc,run[11],c2.w);
        run[12]=fmaf(pc,run[12],c3.x); run[13]=fmaf(pc,run[13],c3.y);
        run[14]=fmaf(pc,run[14],c3.z); run[15]=fmaf(pc,run[15],c3.w);
        c0=n0v; c1=n1v; c2=n2v; c3=n3v; pc = pcn;
    }
}

// fully parallel correction: y[t] += cumAt[t] * (C_t . S_in)
__global__ __launch_bounds__(256)
void correct_k(float* __restrict__ zx, const float* __restrict__ xc,
               const float* __restrict__ Sl, const float* __restrict__ cumAt,
               int LC, int NCH)
{
    const int h = blockIdx.x, ch = blockIdx.y;
    const int t0 = ch * LC;
    if (t0 >= LTOK || ch == 0) return;
    const int t1 = min(t0 + LC, LTOK);
    const int tid = threadIdx.x;
    const int p = tid >> 2, g = tid & 3, n0 = g << 4;
    const float* sp = Sl + (long)(h * NCH + ch) * 4096 + p * 64 + n0;
    const float4 s0 = *(const float4*)(sp),   s1 = *(const float4*)(sp+4);
    const float4 s2 = *(const float4*)(sp+8), s3 = *(const float4*)(sp+12);
    float* yp = zx + 1024 + h * HD;
    const float* ca = cumAt + (long)h * LTOK;
    for (int t = t0; t < t1; ++t) {
        const float* Cp = xc + (long)t * 128 + 64 + n0;
        const float4 c0 = *(const float4*)(Cp),   c1 = *(const float4*)(Cp+4);
        const float4 c2 = *(const float4*)(Cp+8), c3 = *(const float4*)(Cp+12);
        float u0 = s0.x*c0.x, u1 = s0.y*c0.y, u2 = s0.z*c0.z, u3 = s0.w*c0.w;
        float u4 = s1.x*c1.x, u5 = s1.y*c1.y, u6 = s1.z*c1.z, u7 = s1.w*c1.w;
        float u8 = s2.x*c2.x, u9 = s2.y*c2.y, u10= s2.z*c2.z, u11= s2.w*c2.w;
        float u12= s3.x*c3.x, u13= s3.y*c3.y, u14= s3.z*c3.z, u15= s3.w*c3.w;
        u0+=u1; u2+=u3; u4+=u5; u6+=u7; u8+=u9; u10+=u11; u12+=u13; u14+=u15;
        u0+=u2; u4+=u6; u8+=u10; u12+=u14;
        u0+=u4; u8+=u12;
        float d = u0 + u8;
        d += __shfl_xor(d, 1); d += __shfl_xor(d, 2);
        if (g == 0) yp[(long)t * DPROJ + p] += ca[t] * d;
    }
}

// ---------------- serial fallback scan ----------------
__global__ __launch_bounds__(256)
void scan_serial_k(float* __restrict__ zx, const float* __restrict__ xc,
                   const float* __restrict__ dtv, const float* __restrict__ dAv,
                   const float* __restrict__ cw, const float* __restrict__ cb,
                   const float* __restrict__ Dh, int lay)
{
    const int h = blockIdx.x;
    const float dcoef = Dh[lay * NH + h];
    const int tid = threadIdx.x;
    const int p = tid >> 2, g = tid & 3, n0 = g << 4;
    const int hp = h * HD + p;
    const float4 wt = *(const float4*)(cw + ((long)lay * DXBC + hp) * 4);
    const float cbv = cb[(long)lay * DXBC + hp];
    float xw0 = 0.f, xw1 = 0.f, xw2 = 0.f;
    float s[16];
    #pragma unroll
    for (int i = 0; i < 16; ++i) s[i] = 0.f;
    float* yp = zx + 1024 + h * HD;
    const float* dtp = dtv + h;
    const float* dAp = dAv + h;
    Slot SA, SB;
    slot_load(SA, zx, xc, dtp, dAp, 0, hp, n0);
    slot_load(SB, zx, xc, dtp, dAp, 1, hp, n0);
    for (int t = 0; t < LTOK; t += 2) {
        Slot NA;
        slot_load(NA, zx, xc, dtp, dAp, min(t + 2, LTOK - 1), hp, n0);
        {
            float xcv = fmaf(wt.x, xw0, cbv); xcv = fmaf(wt.y, xw1, xcv);
            xcv = fmaf(wt.z, xw2, xcv);       xcv = fmaf(wt.w, SA.x, xcv);
            const float xs = silu_f(xcv);
            float ys = slot_step_tree(SA, s, SA.dt * xs);
            ys += __shfl_xor(ys, 1); ys += __shfl_xor(ys, 2);
            if (g == 0) yp[(long)t * DPROJ + p] = ys + dcoef * xs;
            xw0 = xw1; xw1 = xw2; xw2 = SA.x;
        }
        SA = NA;
        Slot NB;
        slot_load(NB, zx, xc, dtp, dAp, min(t + 3, LTOK - 1), hp, n0);
        if (t + 1 < LTOK) {
            float xcv = fmaf(wt.x, xw0, cbv); xcv = fmaf(wt.y, xw1, xcv);
            xcv = fmaf(wt.z, xw2, xcv);       xcv = fmaf(wt.w, SB.x, xcv);
            const float xs = silu_f(xcv);
            float ys = slot_step_tree(SB, s, SB.dt * xs);
            ys += __shfl_xor(ys, 1); ys += __shfl_xor(ys, 2);
            if (g == 0) yp[(long)(t + 1) * DPROJ + p] = ys + dcoef * xs;
            xw0 = xw1; xw1 = xw2; xw2 = SB.x;
        }
        SB = NB;
    }
}

// ---------------- gate + RMSNorm (in zx) ----------------
__global__ __launch_bounds__(256)
void gate_rms_k(float* __restrict__ zx, const float* __restrict__ nw, int lay)
{
    const int row = blockIdx.x;
    const int tid = threadIdx.x;
    float* base = zx + (long)row * DPROJ;
    const float4 yv = *(const float4*)(base + 1024 + tid * 4);
    const float4 zv = *(const float4*)(base + tid * 4);
    float4 gg;
    gg.x = yv.x * silu_f(zv.x); gg.y = yv.y * silu_f(zv.y);
    gg.z = yv.z * silu_f(zv.z); gg.w = yv.w * silu_f(zv.w);
    float ss = gg.x*gg.x + gg.y*gg.y + gg.z*gg.z + gg.w*gg.w;
    #pragma unroll
    for (int o = 1; o < 64; o <<= 1) ss += __shfl_xor(ss, o);
    __shared__ float red[4];
    if ((tid & 63) == 0) red[tid >> 6] = ss;
    __syncthreads();
    const float tot = red[0] + red[1] + red[2] + red[3];
    const float r = rsqrtf(tot * (1.f / 1024.f) + 1e-5f);
    const float4 w = *(const float4*)(nw + (long)lay * DI + tid * 4);
    gg.x *= r * w.x; gg.y *= r * w.y; gg.z *= r * w.z; gg.w *= r * w.w;
    *(float4*)(base + 1024 + tid * 4) = gg;
}

// ---------------- LayerNorm (512) ----------------
__global__ void ln_k(const float* __restrict__ h, const float* __restrict__ w,
                     const float* __restrict__ b, float* __restrict__ o)
{
    const int t = blockIdx.x;
    const int tid = threadIdx.x;   // 128
    const float* row = h + (long)t * DM;
    const float4 v = *(const float4*)(row + tid * 4);
    float s1 = v.x + v.y + v.z + v.w;
    float s2 = v.x*v.x + v.y*v.y + v.z*v.z + v.w*v.w;
    #pragma unroll
    for (int oo = 1; oo < 64; oo <<= 1) { s1 += __shfl_xor(s1, oo); s2 += __shfl_xor(s2, oo); }
    __shared__ float r1[2], r2[2];
    if ((tid & 63) == 0) { r1[tid >> 6] = s1; r2[tid >> 6] = s2; }
    __syncthreads();
    s1 = r1[0] + r1[1]; s2 = r2[0] + r2[1];
    const float mu = s1 * (1.f / 512.f);
    const float var = s2 * (1.f / 512.f) - mu * mu;
    const float rs = rsqrtf(var + 1e-5f);
    const float4 w4 = *(const float4*)(w + tid * 4);
    const float4 b4 = *(const float4*)(b + tid * 4);
    float4 out;
    out.x = (v.x - mu) * rs * w4.x + b4.x;
    out.y = (v.y - mu) * rs * w4.y + b4.y;
    out.z = (v.z - mu) * rs * w4.z + b4.z;
    out.w = (v.w - mu) * rs * w4.w + b4.w;
    *(float4*)(o + (long)t * DM + tid * 4) = out;
}

__global__ void score_k(const float* __restrict__ t1, const float* __restrict__ w2,
                        const float* __restrict__ b2, float* __restrict__ sc)
{
    const int tok = blockIdx.x * 4 + (threadIdx.x >> 6);
    const int lane = threadIdx.x & 63;
    const float2 v = *(const float2*)(t1 + (long)tok * 128 + lane * 2);
    const float2 w = *(const float2*)(w2 + lane * 2);
    float s = v.x * w.x + v.y * w.y;
    #pragma unroll
    for (int o = 1; o < 64; o <<= 1) s += __shfl_xor(s, o);
    if (lane == 0) sc[tok] = s + b2[0];
}

__global__ void softmax_k(float* __restrict__ sc, int n)
{
    const int tid = threadIdx.x;   // 1024
    float m = -1e30f;
    for (int i = tid; i < n; i += 1024) m = fmaxf(m, sc[i]);
    #pragma unroll
    for (int o = 1; o < 64; o <<= 1) m = fmaxf(m, __shfl_xor(m, o));
    __shared__ float red[16];
    if ((tid & 63) == 0) red[tid >> 6] = m;
    __syncthreads();
    float M = red[0];
    #pragma unroll
    for (int i = 1; i < 16; ++i) M = fmaxf(M, red[i]);
    float s = 0.f;
    for (int i = tid; i < n; i += 1024) s += expf(sc[i] - M);
    #pragma unroll
    for (int o = 1; o < 64; o <<= 1) s += __shfl_xor(s, o);
    __shared__ float red2[16];
    if ((tid & 63) == 0) red2[tid >> 6] = s;
    __syncthreads();
    float S = 0.f;
    #pragma unroll
    for (int i = 0; i < 16; ++i) S += red2[i];
    const float inv = 1.f / S;
    for (int i = tid; i < n; i += 1024) sc[i] = expf(sc[i] - M) * inv;
}

__global__ void zero_k(float* __restrict__ p) { p[threadIdx.x] = 0.f; }

__global__ void pool_k(const float* __restrict__ hn, const float* __restrict__ sc,
                       float* __restrict__ pooled)
{
    const int d = threadIdx.x;       // 512
    const int t0 = blockIdx.x * 500; // 60 blocks
    float acc = 0.f;
    for (int t = t0; t < t0 + 500; ++t)
        acc = fmaf(sc[t], hn[(long)t * DM + d], acc);
    atomicAdd(&pooled[d], acc);
}

__global__ void head_k(const float* __restrict__ pooled, const float* __restrict__ cw,
                       const float* __restrict__ cb, float* __restrict__ out)
{
    const int lane = threadIdx.x;    // 64
    float a0 = 0.f, a1 = 0.f;
    for (int d = lane; d < 512; d += 64) {
        const float pv = pooled[d];
        a0 = fmaf(pv, cw[d], a0);
        a1 = fmaf(pv, cw[512 + d], a1);
    }
    #pragma unroll
    for (int o = 1; o < 64; o <<= 1) { a0 += __shfl_xor(a0, o); a1 += __shfl_xor(a1, o); }
    if (lane == 0) {
        const float l0 = a0 + cb[0], l1 = a1 + cb[1];
        out[0] = l0; out[1] = l1;
        const float m = fmaxf(l0, l1);
        const float e0 = expf(l0 - m), e1 = expf(l1 - m);
        const float inv = 1.f / (e0 + e1);
        out[2] = e0 * inv; out[3] = e1 * inv;
    }
}

extern "C" void kernel_launch(void* const* d_in, const int* in_sizes, int n_in,
                              void* d_out, int out_size, void* d_ws, size_t ws_size,
                              hipStream_t stream)
{
    const float* x         = (const float*)d_in[0];
    const float* fc1_w     = (const float*)d_in[1];
    const float* fc1_b     = (const float*)d_in[2];
    const float* in_proj_w = (const float*)d_in[3];
    const float* conv_w    = (const float*)d_in[4];
    const float* conv_b    = (const float*)d_in[5];
    const float* dt_bias   = (const float*)d_in[6];
    const float* A_log     = (const float*)d_in[7];
    const float* Dh        = (const float*)d_in[8];
    const float* norm_w    = (const float*)d_in[9];
    const float* out_proj_w= (const float*)d_in[10];
    const float* ln_w      = (const float*)d_in[11];
    const float* ln_b      = (const float*)d_in[12];
    const float* attn_w1   = (const float*)d_in[13];
    const float* attn_b1   = (const float*)d_in[14];
    const float* attn_w2   = (const float*)d_in[15];
    const float* attn_b2   = (const float*)d_in[16];
    const float* cls_w     = (const float*)d_in[17];
    const float* cls_b     = (const float*)d_in[18];
    float* out = (float*)d_out;

    // ---- workspace layout (floats) ----
    float* ws = (float*)d_ws;
    float* hb    = ws;                                 // 15,360,000
    float* zx    = hb    + 15360000L;                  // 21,920,000
    float* xc    = zx    + 21920000L;                  // 1,280,000
    float* dtv   = xc    + 1280000L;                   // 160,000
    float* dAv   = dtv   + 160000L;                    // 160,000
    float* cumAt = dAv   + 160000L;                    // 160,000
    float* w2f   = cumAt + 160000L;                    // 1,122,304 floats (2,244,608 ushort)
    float* big   = w2f   + 1122304L;                   // A2 | (Sl,Pc,xh)
    const long fixed_f = 15360000L + 21920000L + 1280000L + 160000L + 160000L
                       + 160000L + 1122304L;
    const long bigf = (long)(ws_size / 4) - fixed_f;

    int NCH = 0;
    if (bigf > 3200) NCH = (int)((bigf - 3200) / 68608L);
    if (NCH > NCH_MAX) NCH = NCH_MAX;
    const int LC = (NCH >= 2) ? (LTOK + NCH - 1) / NCH : LTOK;
    float* Sl = big;
    float* Pc = big + (long)NCH * 65536L;
    float* xh = Pc + (long)NH * NCH;

    // A2 max need: 10000 x 2048 ushorts = 10.24M floats (K=1024 path)
    const bool USE_MFMA = (bigf >= 10250000L);
    unsigned short* A2u = (unsigned short*)big;
    unsigned short* W2u = (unsigned short*)w2f;

    float* h0  = zx;
    float* hn  = zx;
    float* t1  = zx + (long)NBR * LTOK * DM;
    float* sc  = t1 + (long)NBR * LTOK * 128;
    float* pooled = sc + NBR * LTOK;

    // ---- 1. FC1 + ReLU (single pass, K=1024) ----
    if (USE_MFMA) {
        cvt_split_k<<<dim3(10000), 256, 0, stream>>>(x, 1024, LTOK, 1024, A2u, 2048);
        cvt_split_k<<<dim3(512), 256, 0, stream>>>(fc1_w, 1024, 512, 1024, W2u, 2048);
        gemm_mfma_k<1, false, true><<<dim3(4, 79), 256, 0, stream>>>(
            A2u, 2048, W2u, 2048, fc1_b, h0, LTOK, DM, 1024, DM);
    } else {
        gemm_k<1, false, true><<<dim3(8, 157), 256, 0, stream>>>(
            x, fc1_w, fc1_b, h0, LTOK, DM, 1024, 1024, DM);
    }

    // ---- 2. build 3 branch streams ----
    build_branches_k<<<dim3((LTOK * DM + 255) / 256), 256, 0, stream>>>(h0, hb);

    // ---- 3. mamba phase: 3 branches x 2 layers ----
    for (int br = 0; br < NBR; ++br) {
        for (int ml = 0; ml < 2; ++ml) {
            const int lay = br * 2 + ml;
            if (USE_MFMA) {
                cvt_split_k<<<dim3(5000), 256, 0, stream>>>(
                    hb + (long)br * LTOK * DM, 512, LTOK, 512, A2u, 1024);
                cvt_split_k<<<dim3(1096), 256, 0, stream>>>(
                    in_proj_w + (long)lay * DPROJ * DM, 512, DPROJ, 512, W2u, 1024);
                gemm_mfma_k<0, false, false><<<dim3(18, 79), 256, 0, stream>>>(
                    A2u, 1024, W2u, 1024, nullptr, zx, LTOK, DPROJ, 512, DPROJ);
            } else {
                gemm_k<0, false, false><<<dim3(35, 157), 256, 0, stream>>>(
                    hb + (long)br * LTOK * DM,
                    in_proj_w + (long)lay * DPROJ * DM, nullptr, zx,
                    LTOK, DPROJ, DM, DM, DPROJ);
            }
            convBC_k<<<dim3(LTOK * 32 / 256), 256, 0, stream>>>(zx, conv_w, conv_b, xc, lay);
            dt_k<<<dim3(LTOK * NH / 256), 256, 0, stream>>>(zx, dt_bias, A_log, dtv, dAv, lay);
            if (NCH >= 2) {
                halo_k<<<dim3((NCH * 1024 + 255) / 256), 256, 0, stream>>>(zx, xh, LC, NCH);
                scan_local_k<<<dim3(NH, NCH), 256, 0, stream>>>(
                    zx, xc, dtv, dAv, conv_w, conv_b, Dh, Sl, Pc, xh, cumAt, lay, LC, NCH);
                combine_k<<<dim3(NH), 256, 0, stream>>>(Sl, Pc, NCH);
                correct_k<<<dim3(NH, NCH), 256, 0, stream>>>(zx, xc, Sl, cumAt, LC, NCH);
            } else {
                scan_serial_k<<<dim3(NH), 256, 0, stream>>>(
                    zx, xc, dtv, dAv, conv_w, conv_b, Dh, lay);
            }
            gate_rms_k<<<dim3(LTOK), 256, 0, stream>>>(zx, norm_w, lay);
            if (USE_MFMA) {
                cvt_split_k<<<dim3(10000), 256, 0, stream>>>(
                    zx + 1024, DPROJ, LTOK, 1024, A2u, 2048);
                cvt_split_k<<<dim3(512), 256, 0, stream>>>(
                    out_proj_w + (long)lay * DM * DI, 1024, 512, 1024, W2u, 2048);
                gemm_mfma_k<0, true, false><<<dim3(4, 79), 256, 0, stream>>>(
                    A2u, 2048, W2u, 2048, nullptr, hb + (long)br * LTOK * DM,
                    LTOK, DM, 1024, DM);
            } else {
                gemm_k<0, true, false><<<dim3(8, 157), 256, 0, stream>>>(
                    zx + 1024, out_proj_w + (long)lay * DM * DI, nullptr,
                    hb + (long)br * LTOK * DM, LTOK, DM, DI, DPROJ, DM);
            }
        }
    }

    // ---- 4. final LN ----
    ln_k<<<dim3(NBR * LTOK), 128, 0, stream>>>(hb, ln_w, ln_b, hn);

    // ---- 5. attention scores (small; fp32) ----
    gemm_k<2, false, true><<<dim3(2, 469), 256, 0, stream>>>(
        hn, attn_w1, attn_b1, t1, NBR * LTOK, 128, DM, DM, 128);
    score_k<<<dim3(NBR * LTOK / 4), 256, 0, stream>>>(t1, attn_w2, attn_b2, sc);
    softmax_k<<<dim3(1), 1024, 0, stream>>>(sc, NBR * LTOK);

    // ---- 6. pooling + head ----
    zero_k<<<dim3(1), 512, 0, stream>>>(pooled);
    pool_k<<<dim3(60), 512, 0, stream>>>(hn, sc, pooled);
    head_k<<<dim3(1), 64, 0, stream>>>(pooled, cls_w, cls_b, out);
}